// Round 3
// baseline (128.768 us; speedup 1.0000x reference)
//
#include <hip/hip_runtime.h>

// LengthRegulator: expanded[b,pos,:] = encoder_out[b, searchsorted(cum_dur[b], pos, 'right'), :]
// for pos < min(mel_len, max_len), else 0; mel_lens[b] = cum_dur[b, T-1].
//
// Shapes fixed by the reference: B=16, T=512, D=384; max_len derived from out_size.
// d_out layout: [B*max_len*D floats expanded][B floats mel_lens].
//
// v3: two-kernel split.
//  K1 (16 blocks): per-batch scan + searchsorted -> tok[b][pos] table in d_ws
//     (tok = -1 for pos >= min(mel,max_len)); writes mel_lens tail.
//  K2 (4096 blocks x 256 thr): pure streaming copy - no scan, no binary
//     search, 16 frames/block, 2x oversubscription for load balance,
//     nontemporal stores (96 MiB stream >> 32 MiB L2; keep L2 for enc+tok).
//  Rationale: v1 (18-barrier scan) and v2 (3-barrier scan + nt) measured
//  identical -> per-block preamble/cache policy was not the limiter tested;
//  this removes ALL per-block non-streaming work and the exact-capacity
//  grid (1024 blk x 8 waves = machine capacity, no backfill) of v1/v2.
//  Falls back to the v2 single kernel if ws_size is too small.

#define LR_B       16
#define LR_T       512
#define LR_D4      96          // D/4 float4s per frame (D=384)
#define LR_THREADS 512
#define LR_WAVES   (LR_THREADS / 64)

#define K2_THREADS 256
#define K2_FRAMES  16          // frames per K2 block; 16*96/256 = 6 f4/thread

typedef float f32x4 __attribute__((ext_vector_type(4)));

// ---------------- K1: tok-table precompute (one block per batch) ----------------
__global__ __launch_bounds__(LR_THREADS)
void lr_tok_kernel(const int* __restrict__ dur,   // [B*T]
                   int*       __restrict__ tok,   // [B*max_len] out (-1 = zero frame)
                   float*     __restrict__ out,   // for mel_lens tail
                   int max_len) {
    const int b    = blockIdx.x;
    const int tid  = threadIdx.x;
    const int lane = tid & 63;
    const int wid  = tid >> 6;

    __shared__ int s_cum[LR_T];
    __shared__ int s_wsum[LR_WAVES];

    // inclusive scan of duration row: wave shuffles, 2 barriers
    int v = dur[b * LR_T + tid];
#pragma unroll
    for (int off = 1; off < 64; off <<= 1) {
        int n = __shfl_up(v, off, 64);
        if (lane >= off) v += n;
    }
    if (lane == 63) s_wsum[wid] = v;
    __syncthreads();
    int woff = 0;
#pragma unroll
    for (int w = 0; w < LR_WAVES; ++w)
        woff += (w < wid) ? s_wsum[w] : 0;
    s_cum[tid] = v + woff;
    __syncthreads();

    const int mel_raw = s_cum[LR_T - 1];
    const int mel     = min(mel_raw, max_len);

    if (tid == 0) {
        out[(size_t)LR_B * max_len * (LR_D4 * 4) + b] = (float)mel_raw;
    }

    // tok[pos] = upper_bound(cum, pos) clipped, or -1 past mel
    for (int pos = tid; pos < max_len; pos += LR_THREADS) {
        int t = -1;
        if (pos < mel) {
            int lo = 0, hi = LR_T;
            while (lo < hi) {
                int mid = (lo + hi) >> 1;
                if (s_cum[mid] <= pos) lo = mid + 1; else hi = mid;
            }
            t = min(lo, LR_T - 1);
        }
        tok[b * max_len + pos] = t;   // coalesced, normal stores (L2-hot for K2)
    }
}

// ---------------- K2: pure streaming expand ----------------
__global__ __launch_bounds__(K2_THREADS)
void lr_copy_kernel(const f32x4* __restrict__ enc,   // [B*T*D4]
                    const int*   __restrict__ tok,   // [B*max_len]
                    float*       __restrict__ out,
                    int max_len) {
    const int b    = blockIdx.y;
    const int pos0 = blockIdx.x * K2_FRAMES;
    const int tid  = threadIdx.x;

    __shared__ int s_tok[K2_FRAMES];
    if (tid < K2_FRAMES) {
        int pos = pos0 + tid;
        s_tok[tid] = (pos < max_len) ? tok[b * max_len + pos] : -1;
    }
    __syncthreads();

    f32x4* out4 = (f32x4*)out;
    const size_t out_base = ((size_t)b * max_len + pos0) * LR_D4;
    const f32x4 zero4 = {0.f, 0.f, 0.f, 0.f};

#pragma unroll
    for (int it = 0; it < (K2_FRAMES * LR_D4) / K2_THREADS; ++it) {
        int j   = it * K2_THREADS + tid;
        int f   = j / LR_D4;
        int d4  = j - f * LR_D4;
        int pos = pos0 + f;
        if (pos >= max_len) continue;
        int t = s_tok[f];
        f32x4 val = zero4;
        if (t >= 0) {
            val = enc[(size_t)(b * LR_T + t) * LR_D4 + d4];
        }
        __builtin_nontemporal_store(val, &out4[out_base + j]);
    }
}

// ---------------- fallback: v2 single kernel (if ws too small) ----------------
__global__ __launch_bounds__(LR_THREADS)
void lr_expand_kernel(const f32x4* __restrict__ enc,
                      const int*   __restrict__ dur,
                      float*       __restrict__ out,
                      int max_len) {
    const int b    = blockIdx.y;
    const int pos0 = blockIdx.x * 64;
    const int tid  = threadIdx.x;
    const int lane = tid & 63;
    const int wid  = tid >> 6;

    __shared__ int s_cum[LR_T];
    __shared__ int s_wsum[LR_WAVES];
    __shared__ int s_tok[64];

    int v = dur[b * LR_T + tid];
#pragma unroll
    for (int off = 1; off < 64; off <<= 1) {
        int n = __shfl_up(v, off, 64);
        if (lane >= off) v += n;
    }
    if (lane == 63) s_wsum[wid] = v;
    __syncthreads();
    int woff = 0;
#pragma unroll
    for (int w = 0; w < LR_WAVES; ++w)
        woff += (w < wid) ? s_wsum[w] : 0;
    s_cum[tid] = v + woff;
    __syncthreads();

    const int mel_raw = s_cum[LR_T - 1];
    const int mel     = min(mel_raw, max_len);

    if (blockIdx.x == 0 && tid == 0) {
        out[(size_t)LR_B * max_len * (LR_D4 * 4) + b] = (float)mel_raw;
    }

    f32x4* out4 = (f32x4*)out;
    const size_t out_base = ((size_t)b * max_len + pos0) * LR_D4;
    const f32x4 zero4 = {0.f, 0.f, 0.f, 0.f};

    if (pos0 >= mel) {
#pragma unroll
        for (int it = 0; it < (64 * LR_D4) / LR_THREADS; ++it) {
            int j   = it * LR_THREADS + tid;
            int f   = j / LR_D4;
            int pos = pos0 + f;
            if (pos >= max_len) continue;
            __builtin_nontemporal_store(zero4, &out4[out_base + j]);
        }
        return;
    }

    if (tid < 64) {
        int pos = pos0 + tid;
        int lo = 0, hi = LR_T;
        while (lo < hi) {
            int mid = (lo + hi) >> 1;
            if (s_cum[mid] <= pos) lo = mid + 1; else hi = mid;
        }
        s_tok[tid] = min(lo, LR_T - 1);
    }
    __syncthreads();

#pragma unroll
    for (int it = 0; it < (64 * LR_D4) / LR_THREADS; ++it) {
        int j   = it * LR_THREADS + tid;
        int f   = j / LR_D4;
        int d4  = j - f * LR_D4;
        int pos = pos0 + f;
        if (pos >= max_len) continue;
        f32x4 val = zero4;
        if (pos < mel) {
            val = enc[(size_t)(b * LR_T + s_tok[f]) * LR_D4 + d4];
        }
        __builtin_nontemporal_store(val, &out4[out_base + j]);
    }
}

extern "C" void kernel_launch(void* const* d_in, const int* in_sizes, int n_in,
                              void* d_out, int out_size, void* d_ws, size_t ws_size,
                              hipStream_t stream) {
    const f32x4* enc = (const f32x4*)d_in[0];   // encoder_out f32 [B,T,D]
    const int*   dur = (const int*)d_in[1];     // durations i32 [B,T]
    float*       out = (float*)d_out;

    // out_size = B*max_len*D + B (floats) -> max_len
    const int max_len = (out_size - LR_B) / (LR_B * LR_D4 * 4);

    const size_t ws_need = (size_t)LR_B * max_len * sizeof(int);
    if (d_ws != nullptr && ws_size >= ws_need) {
        int* tok = (int*)d_ws;
        lr_tok_kernel<<<LR_B, LR_THREADS, 0, stream>>>(dur, tok, out, max_len);
        dim3 g2((max_len + K2_FRAMES - 1) / K2_FRAMES, LR_B);
        lr_copy_kernel<<<g2, K2_THREADS, 0, stream>>>(enc, tok, out, max_len);
    } else {
        dim3 grid((max_len + 63) / 64, LR_B);
        lr_expand_kernel<<<grid, LR_THREADS, 0, stream>>>(enc, dur, out, max_len);
    }
}